// Round 8
// baseline (414.198 us; speedup 1.0000x reference)
//
#include <hip/hip_runtime.h>
#include <hip/hip_bf16.h>
#include <math.h>

#define B_SZ 4
#define LSEQ 2048
#define DM 1024
#define DI 2048
#define DH 1024
#define DS 16
#define DTR 64
#define RTOT 96
#define MROWS (B_SZ * LSEQ) /* 8192 */

// scan chunking
#define NCH 32
#define CHUNK 64 /* LSEQ / NCH */

typedef short bf8_t __attribute__((ext_vector_type(8)));
typedef float f4_t __attribute__((ext_vector_type(4)));

__device__ __forceinline__ unsigned short f2bfbits(float v) {
  __hip_bfloat16 h = __float2bfloat16(v);
  return *(unsigned short*)&h;
}

// async global->LDS 16B per lane; LDS dest is wave-uniform base + lane*16
__device__ __forceinline__ void gl_lds16(const void* g, void* l) {
  __builtin_amdgcn_global_load_lds(
      (const __attribute__((address_space(1))) unsigned int*)g,
      (__attribute__((address_space(3))) unsigned int*)l,
      16, 0, 0);
}

__device__ __forceinline__ void ld8f(const float* p, unsigned short* d) {
  const float4 a = ((const float4*)p)[0];
  const float4 b = ((const float4*)p)[1];
  d[0] = f2bfbits(a.x); d[1] = f2bfbits(a.y); d[2] = f2bfbits(a.z); d[3] = f2bfbits(a.w);
  d[4] = f2bfbits(b.x); d[5] = f2bfbits(b.y); d[6] = f2bfbits(b.z); d[7] = f2bfbits(b.w);
}

// ---------------- dtype probe (1 = bf16 inputs, 0 = fp32 inputs) ----------------
__global__ void probe_kernel(const unsigned short* __restrict__ p, int* __restrict__ flag) {
  int lane = threadIdx.x;  // 64 lanes
  int sane = 0;
#pragma unroll
  for (int j = 0; j < 4; j++) {
    unsigned short lo = p[(lane * 4 + j) * 2];
    int e = (lo >> 7) & 0xFF;
    sane += (e <= 130) ? 1 : 0;
  }
  sane += __shfl_xor(sane, 1, 64);
  sane += __shfl_xor(sane, 2, 64);
  sane += __shfl_xor(sane, 4, 64);
  sane += __shfl_xor(sane, 8, 64);
  sane += __shfl_xor(sane, 16, 64);
  sane += __shfl_xor(sane, 32, 64);
  if (lane == 0) *flag = (sane >= 220) ? 1 : 0;
}

// ---------------- prep: canonicalize small weights to fp32 ----------------
// segments: conv_xw 4096 | conv_xb 1024 | conv_zw 4096 | conv_zb 1024 |
//           W_dt 65536 | inv_dt 1024 | Dvec 1024 | b_out 1024
#define PREP_TOT 78848
__global__ __launch_bounds__(256) void prep_kernel(
    const int* __restrict__ flag,
    const void* s0, const void* s1, const void* s2, const void* s3,
    const void* s4, const void* s5, const void* s6, const void* s7,
    float* __restrict__ out) {
  int i = blockIdx.x * 256 + threadIdx.x;
  if (i >= PREP_TOT) return;
  const void* src; int off;
  if      (i < 4096)   { src = s0; off = i; }
  else if (i < 5120)   { src = s1; off = i - 4096; }
  else if (i < 9216)   { src = s2; off = i - 5120; }
  else if (i < 10240)  { src = s3; off = i - 9216; }
  else if (i < 75776)  { src = s4; off = i - 10240; }
  else if (i < 76800)  { src = s5; off = i - 75776; }
  else if (i < 77824)  { src = s6; off = i - 76800; }
  else                 { src = s7; off = i - 77824; }
  float v = (*flag == 1) ? __bfloat162float(((const __hip_bfloat16*)src)[off])
                         : ((const float*)src)[off];
  out[i] = v;
}

// ---------------- transpose: Wt[n][k] bf16 <- W[k][n] (dtype by flag) ----------------
__global__ __launch_bounds__(256) void transpose_kernel(
    const int* __restrict__ flag, const void* __restrict__ W,
    unsigned short* __restrict__ Wt, int K, int N) {
  __shared__ unsigned short tile[32][33];
  int n0 = blockIdx.x * 32, k0 = blockIdx.y * 32;
  int c = threadIdx.x & 31, r8 = threadIdx.x >> 5;
  bool isbf = (*flag == 1);
#pragma unroll
  for (int p = 0; p < 4; p++) {
    int r = r8 + p * 8;
    unsigned short v;
    if (isbf) v = ((const unsigned short*)W)[(size_t)(k0 + r) * N + n0 + c];
    else      v = f2bfbits(((const float*)W)[(size_t)(k0 + r) * N + n0 + c]);
    tile[r][c] = v;
  }
  __syncthreads();
#pragma unroll
  for (int p = 0; p < 4; p++) {
    int r = r8 + p * 8;
    Wt[(size_t)(n0 + r) * K + k0 + c] = tile[c][r];
  }
}

// transpose W_xdbl [1024][96] -> Wxt [128][1024] bf16, rows 96..127 zero
__global__ __launch_bounds__(256) void transpose_pad_kernel(
    const int* __restrict__ flag, const void* __restrict__ W,
    unsigned short* __restrict__ Wt) {
  __shared__ unsigned short tile[32][33];
  int n0 = blockIdx.x * 32, k0 = blockIdx.y * 32;
  int c = threadIdx.x & 31, r8 = threadIdx.x >> 5;
  bool isbf = (*flag == 1);
#pragma unroll
  for (int p = 0; p < 4; p++) {
    int r = r8 + p * 8;
    unsigned short v = 0;
    if (n0 + c < RTOT) {
      if (isbf) v = ((const unsigned short*)W)[(size_t)(k0 + r) * RTOT + n0 + c];
      else      v = f2bfbits(((const float*)W)[(size_t)(k0 + r) * RTOT + n0 + c]);
    }
    tile[r][c] = v;
  }
  __syncthreads();
#pragma unroll
  for (int p = 0; p < 4; p++) {
    int r = r8 + p * 8;
    Wt[(size_t)(n0 + r) * DH + k0 + c] = tile[c][r];
  }
}

// ---------------- MFMA GEMM (B^T): C[M,N] = A[M,K] @ Bt[N,K]^T (+bias) ----------------
// 128x128 tile, BK=32, 4 waves 2x2, wave 64x64 = 4x4 mfma_f32_16x16x32_bf16.
// Unpadded LDS, XOR-swizzled 16B chunks: chunk' = ki ^ ((row>>1)&3).
// XCD-aware block swizzle: each XCD (L&7 under round-robin dispatch) owns a
// contiguous slice of M-bands so its L2 holds A-slice (2MB) + full B (4MB).
template <bool A_BF, bool O_BF>
__global__ __launch_bounds__(256) void gemm_tpl(
    const int* __restrict__ flag, int want,
    const void* __restrict__ A, const unsigned short* __restrict__ Bt,
    const float* __restrict__ bias, void* __restrict__ C,
    int M, int N, int K) {
  if (*flag != want) return;
  __shared__ __align__(16) unsigned short As[128 * 32];
  __shared__ __align__(16) unsigned short Bs[128 * 32];
  const int tid = threadIdx.x;
  const int lane = tid & 63;
  const int wave = tid >> 6;
  const int quad = lane >> 4;
  const int l16 = lane & 15;
  const int wm = (wave & 1) * 64;
  const int wn = (wave >> 1) * 64;

  // XCD swizzle (MB % 8 == 0 for all call sites)
  const int NB = gridDim.x, MB = gridDim.y;
  int L = blockIdx.y * NB + blockIdx.x;
  int xcd = L & 7;
  int w = L >> 3;
  int m_band = xcd * (MB >> 3) + (w / NB);
  int n_blk = w % NB;
  const int m0 = m_band * 128;
  const int n0 = n_blk * 128;

  f4_t acc[4][4] = {};

  for (int k0 = 0; k0 < K; k0 += 32) {
#pragma unroll
    for (int j = 0; j < 2; j++) {
      int ch = tid + j * 256;
      int mi = ch >> 2;
      int ki = (ch & 3) ^ ((mi >> 1) & 3);
      if (A_BF) {
        gl_lds16((const unsigned short*)A + (size_t)(m0 + mi) * K + k0 + ki * 8,
                 &As[(j * 256 + wave * 64) * 8]);
      } else {
        unsigned short tmp[8];
        ld8f((const float*)A + (size_t)(m0 + mi) * K + k0 + ki * 8, tmp);
        *(uint4*)&As[ch * 8] = *(uint4*)tmp;
      }
    }
#pragma unroll
    for (int j = 0; j < 2; j++) {
      int ch = tid + j * 256;
      int ni = ch >> 2;
      int ki = (ch & 3) ^ ((ni >> 1) & 3);
      gl_lds16(Bt + (size_t)(n0 + ni) * K + k0 + ki * 8,
               &Bs[(j * 256 + wave * 64) * 8]);
    }
    __syncthreads();

    bf8_t af[4], bfr[4];
#pragma unroll
    for (int ti = 0; ti < 4; ti++) {
      int r = wm + ti * 16 + l16;
      af[ti] = *(const bf8_t*)&As[(r * 4 + (quad ^ ((r >> 1) & 3))) * 8];
    }
#pragma unroll
    for (int tj = 0; tj < 4; tj++) {
      int r = wn + tj * 16 + l16;
      bfr[tj] = *(const bf8_t*)&Bs[(r * 4 + (quad ^ ((r >> 1) & 3))) * 8];
    }
#pragma unroll
    for (int ti = 0; ti < 4; ti++)
#pragma unroll
      for (int tj = 0; tj < 4; tj++)
        acc[ti][tj] = __builtin_amdgcn_mfma_f32_16x16x32_bf16(
            af[ti], bfr[tj], acc[ti][tj], 0, 0, 0);
    __syncthreads();
  }

  // epilogue: C/D layout col=lane&15, row=quad*4+reg (verified m89/m91)
#pragma unroll
  for (int ti = 0; ti < 4; ti++) {
#pragma unroll
    for (int tj = 0; tj < 4; tj++) {
      int col = n0 + wn + tj * 16 + l16;
      float bv = bias ? bias[col] : 0.f;
#pragma unroll
      for (int r = 0; r < 4; r++) {
        int row = m0 + wm + ti * 16 + quad * 4 + r;
        float v = acc[ti][tj][r] + bv;
        if (O_BF) ((__hip_bfloat16*)C)[(size_t)row * N + col] = __float2bfloat16(v);
        else      ((float*)C)[(size_t)row * N + col] = v;
      }
    }
  }
}

// ---------------- xdbl MFMA: xdbl[M,96] = xs_bf[M,1024] @ Wxt[96,1024]^T ----------------
__global__ __launch_bounds__(256) void xdbl_mfma_kernel(
    const unsigned short* __restrict__ A, const unsigned short* __restrict__ Bt,
    float* __restrict__ xdbl) {
  __shared__ __align__(16) unsigned short As[64 * 32];
  __shared__ __align__(16) unsigned short Bs[128 * 32];
  const int tid = threadIdx.x;
  const int lane = tid & 63;
  const int wave = tid >> 6;
  const int quad = lane >> 4;
  const int l16 = lane & 15;
  const int m0 = blockIdx.x * 64;

  f4_t acc[6] = {};

  for (int k0 = 0; k0 < DH; k0 += 32) {
    {
      int ch = tid;  // 256 chunks for A
      int mi = ch >> 2;
      int ki = (ch & 3) ^ ((mi >> 1) & 3);
      gl_lds16(A + (size_t)(m0 + mi) * DH + k0 + ki * 8, &As[(wave * 64) * 8]);
    }
#pragma unroll
    for (int j = 0; j < 2; j++) {
      int ch = tid + j * 256;
      int ni = ch >> 2;
      int ki = (ch & 3) ^ ((ni >> 1) & 3);
      gl_lds16(Bt + (size_t)ni * DH + k0 + ki * 8, &Bs[(j * 256 + wave * 64) * 8]);
    }
    __syncthreads();

    bf8_t af, bfr[6];
    {
      int r = wave * 16 + l16;
      af = *(const bf8_t*)&As[(r * 4 + (quad ^ ((r >> 1) & 3))) * 8];
    }
#pragma unroll
    for (int tj = 0; tj < 6; tj++) {
      int r = tj * 16 + l16;
      bfr[tj] = *(const bf8_t*)&Bs[(r * 4 + (quad ^ ((r >> 1) & 3))) * 8];
    }
#pragma unroll
    for (int tj = 0; tj < 6; tj++)
      acc[tj] = __builtin_amdgcn_mfma_f32_16x16x32_bf16(af, bfr[tj], acc[tj], 0, 0, 0);
    __syncthreads();
  }

#pragma unroll
  for (int tj = 0; tj < 6; tj++) {
    int col = tj * 16 + l16;
#pragma unroll
    for (int r = 0; r < 4; r++) {
      int row = m0 + wave * 16 + quad * 4 + r;
      xdbl[(size_t)row * RTOT + col] = acc[tj][r];
    }
  }
}

// ---------------- depthwise conv (k=4, SAME: pad_low=1) + SiLU, both halves ----------------
__global__ __launch_bounds__(256) void conv_silu_kernel(
    const __hip_bfloat16* __restrict__ xz,
    const float* __restrict__ wx, const float* __restrict__ bx,
    const float* __restrict__ wz, const float* __restrict__ bz,
    __hip_bfloat16* __restrict__ xs_bf, __hip_bfloat16* __restrict__ cat) {
  int gid = blockIdx.x * 256 + threadIdx.x;  // M*1024 threads
  int c = gid & 1023;
  int m = gid >> 10;
  int t = m & (LSEQ - 1);
  float ax = bx[c];
  float az = bz[c];
#pragma unroll
  for (int j = 0; j < 4; j++) {
    int tt = t - 1 + j;
    if (tt < 0 || tt >= LSEQ) continue;
    size_t row = (size_t)(m - t + tt);
    float vx = __bfloat162float(xz[row * DI + c]);
    float vz = __bfloat162float(xz[row * DI + DH + c]);
    ax += wx[j * DH + c] * vx;
    az += wz[j * DH + c] * vz;
  }
  float sx = ax / (1.f + __expf(-ax));
  float sz = az / (1.f + __expf(-az));
  xs_bf[(size_t)m * DH + c] = __float2bfloat16(sx);
  cat[(size_t)m * DI + DH + c] = __float2bfloat16(sz);
}

// ---------------- delta = softplus(dt_low @ W_dt + 2*inv_dt), 8 rows/block ----------------
__global__ __launch_bounds__(256) void delta_kernel(
    const float* __restrict__ xdbl, const float* __restrict__ Wdt,
    const float* __restrict__ inv_dt, float* __restrict__ delta) {
  const int d = blockIdx.x * 256 + threadIdx.x;  // blockIdx.x in [0,4)
  const int m0 = blockIdx.y * 8;
  __shared__ float xr[8][DTR];
#pragma unroll
  for (int i = 0; i < 2; i++) {
    int e = threadIdx.x + i * 256;  // 512 = 8*64
    xr[e >> 6][e & 63] = xdbl[(size_t)(m0 + (e >> 6)) * RTOT + (e & 63)];
  }
  __syncthreads();
  float acc[8];
#pragma unroll
  for (int i = 0; i < 8; i++) acc[i] = 0.f;
  for (int rr = 0; rr < DTR; rr++) {
    float w = Wdt[(size_t)rr * DH + d];
#pragma unroll
    for (int i = 0; i < 8; i++) acc[i] = fmaf(xr[i][rr], w, acc[i]);
  }
  const float bias2 = 2.f * inv_dt[d];
#pragma unroll
  for (int i = 0; i < 8; i++) {
    float v = acc[i] + bias2;
    float sp = (v > 0.f) ? (v + log1pf(__expf(-v))) : log1pf(__expf(v));
    delta[(size_t)(m0 + i) * DH + d] = sp;
  }
}

// ---------------- chunked selective scan (u in bf16) ----------------
__global__ __launch_bounds__(256) void scan_pass1(
    const float* __restrict__ delta, const __hip_bfloat16* __restrict__ u,
    const float* __restrict__ xdbl,
    float* __restrict__ Echunks, float* __restrict__ hp) {
  const int tid = threadIdx.x;
  const int d = blockIdx.x * 256 + tid;
  const int c = blockIdx.y, b = blockIdx.z;
  const int row0 = b * LSEQ + c * CHUNK;
  __shared__ float sBC[CHUNK][32];  // [t][0..15]=B, [16..31]=C
#pragma unroll
  for (int i = 0; i < 2; i++) {
    int task = tid + i * 256;
    int r = task >> 3, seg = task & 7;
    *(float4*)&sBC[r][seg * 4] =
        *(const float4*)&xdbl[(size_t)(row0 + r) * RTOT + DTR + seg * 4];
  }
  __syncthreads();
  float h[16];
#pragma unroll
  for (int n = 0; n < 16; n++) h[n] = 0.f;
  float E = 1.f;
  for (int t = 0; t < CHUNK; t++) {
    size_t off = (size_t)(row0 + t) * DH + d;
    float dt = delta[off];
    float ut = __bfloat162float(u[off]);
    float e = __expf(-dt);
    E *= e;
    float du = dt * ut;
    float p = 1.f;
#pragma unroll
    for (int n = 0; n < 16; n++) {
      p *= e;
      h[n] = fmaf(p, h[n], du * sBC[t][n]);
    }
  }
  Echunks[((size_t)c * B_SZ + b) * DH + d] = E;
#pragma unroll
  for (int n = 0; n < 16; n++)
    hp[(((size_t)c * B_SZ + b) * 16 + n) * DH + d] = h[n];
}

__global__ __launch_bounds__(256) void scan_pass2(
    const float* __restrict__ Echunks, const float* __restrict__ hp,
    float* __restrict__ hs) {
  int t = blockIdx.x * 256 + threadIdx.x;
  int d = t & 1023;
  int n = (t >> 10) & 15;
  int b = t >> 14;
  float h = 0.f;
  const int k0 = n + 1;
  for (int c = 0; c < NCH; c++) {
    float E = Echunks[((size_t)c * B_SZ + b) * DH + d];
    float a = 1.f, base = E;
    int k = k0;
#pragma unroll
    for (int i = 0; i < 5; i++) {
      if (k & 1) a *= base;
      base *= base;
      k >>= 1;
    }
    size_t idx = (((size_t)c * B_SZ + b) * 16 + n) * DH + d;
    hs[idx] = h;
    h = fmaf(a, h, hp[idx]);
  }
}

__global__ __launch_bounds__(256) void scan_pass3(
    const float* __restrict__ delta, const __hip_bfloat16* __restrict__ u,
    const float* __restrict__ xdbl, const float* __restrict__ hs,
    const float* __restrict__ Dvec, __hip_bfloat16* __restrict__ cat) {
  const int tid = threadIdx.x;
  const int d = blockIdx.x * 256 + tid;
  const int c = blockIdx.y, b = blockIdx.z;
  const int row0 = b * LSEQ + c * CHUNK;
  __shared__ float sBC[CHUNK][32];
#pragma unroll
  for (int i = 0; i < 2; i++) {
    int task = tid + i * 256;
    int r = task >> 3, seg = task & 7;
    *(float4*)&sBC[r][seg * 4] =
        *(const float4*)&xdbl[(size_t)(row0 + r) * RTOT + DTR + seg * 4];
  }
  __syncthreads();
  float h[16];
#pragma unroll
  for (int n = 0; n < 16; n++)
    h[n] = hs[(((size_t)c * B_SZ + b) * 16 + n) * DH + d];
  const float Dd = Dvec[d];
  for (int t = 0; t < CHUNK; t++) {
    size_t off = (size_t)(row0 + t) * DH + d;
    float dt = delta[off];
    float ut = __bfloat162float(u[off]);
    float e = __expf(-dt);
    float du = dt * ut;
    float p = 1.f, y = 0.f;
#pragma unroll
    for (int n = 0; n < 16; n++) {
      p *= e;
      h[n] = fmaf(p, h[n], du * sBC[t][n]);
      y = fmaf(h[n], sBC[t][16 + n], y);
    }
    y = fmaf(ut, Dd, y);
    cat[(size_t)(row0 + t) * DI + d] = __float2bfloat16(y);
  }
}

extern "C" void kernel_launch(void* const* d_in, const int* in_sizes, int n_in,
                              void* d_out, int out_size, void* d_ws, size_t ws_size,
                              hipStream_t stream) {
  char* ws = (char*)d_ws;
  // layout (MB offsets):
  // [0,32): xz bf16 [8192][2048]; later delta fp32 [8192][1024] (xz dead after conv)
  // [32,48): xs bf16 [8192][1024]
  // [64,96): cat bf16 (y cols 0..1023, z cols 1024..2047)
  // [96,99): xdbl fp32 [8192][96]
  // [99,99.5): Echunks | [100,108): hp | [108,116): hs
  // [116,120): Wt_in bf16 | [120,124): Wt_out bf16 | [124,124.25): Wxt bf16 [128][1024]
  // [125,+316KB): canonical fp32 weights | [126]: flag
  __hip_bfloat16* xz  = (__hip_bfloat16*)(ws);
  float* delta        = (float*)(ws);
  __hip_bfloat16* xs  = (__hip_bfloat16*)(ws + ((size_t)32 << 20));
  __hip_bfloat16* cat = (__hip_bfloat16*)(ws + ((size_t)64 << 20));
  float* xdbl         = (float*)(ws + ((size_t)96 << 20));
  float* Echunks      = (float*)(ws + ((size_t)99 << 20));
  float* hp           = (float*)(ws + ((size_t)100 << 20));
  float* hs           = (float*)(ws + ((size_t)108 << 20));
  unsigned short* Wt_in  = (unsigned short*)(ws + ((size_t)116 << 20));
  unsigned short* Wt_out = (unsigned short*)(ws + ((size_t)120 << 20));
  unsigned short* Wxt    = (unsigned short*)(ws + ((size_t)124 << 20));
  float* cw           = (float*)(ws + ((size_t)125 << 20));
  int* flag           = (int*)(ws + ((size_t)126 << 20));

  const float* conv_xwf = cw + 0;
  const float* conv_xbf = cw + 4096;
  const float* conv_zwf = cw + 5120;
  const float* conv_zbf = cw + 9216;
  const float* Wdtf     = cw + 10240;
  const float* inv_dtf  = cw + 75776;
  const float* Df       = cw + 76800;
  const float* b_outf   = cw + 77824;

  probe_kernel<<<1, 64, 0, stream>>>((const unsigned short*)d_in[0], flag);
  prep_kernel<<<(PREP_TOT + 255) / 256, 256, 0, stream>>>(
      flag, d_in[2], d_in[3], d_in[4], d_in[5], d_in[7], d_in[8], d_in[9],
      d_in[11], cw);
  transpose_kernel<<<dim3(DI / 32, DM / 32), 256, 0, stream>>>(
      flag, d_in[1], Wt_in, DM, DI);
  transpose_kernel<<<dim3(DM / 32, DI / 32), 256, 0, stream>>>(
      flag, d_in[10], Wt_out, DI, DM);
  transpose_pad_kernel<<<dim3(4, DH / 32), 256, 0, stream>>>(flag, d_in[6], Wxt);

  // 1) xz = x @ W_in  (M=8192,N=2048,K=1024), out bf16. Dead-launch dtype variants.
  gemm_tpl<true, true><<<dim3(DI / 128, MROWS / 128), 256, 0, stream>>>(
      flag, 1, d_in[0], Wt_in, (const float*)nullptr, xz, MROWS, DI, DM);
  gemm_tpl<false, true><<<dim3(DI / 128, MROWS / 128), 256, 0, stream>>>(
      flag, 0, d_in[0], Wt_in, (const float*)nullptr, xz, MROWS, DI, DM);
  // 2) conv + silu -> xs bf16, cat z-half
  conv_silu_kernel<<<(MROWS * DH) / 256, 256, 0, stream>>>(
      xz, conv_xwf, conv_xbf, conv_zwf, conv_zbf, xs, cat);
  // 3) x_dbl = xs @ W_xdbl via MFMA
  xdbl_mfma_kernel<<<MROWS / 64, 256, 0, stream>>>(
      (const unsigned short*)xs, Wxt, xdbl);
  // 4) delta (overwrites dead xz region)
  delta_kernel<<<dim3(4, MROWS / 8), 256, 0, stream>>>(xdbl, Wdtf, inv_dtf, delta);
  // 5) chunked scan
  scan_pass1<<<dim3(4, NCH, B_SZ), 256, 0, stream>>>(delta, xs, xdbl, Echunks, hp);
  scan_pass2<<<256, 256, 0, stream>>>(Echunks, hp, hs);
  scan_pass3<<<dim3(4, NCH, B_SZ), 256, 0, stream>>>(delta, xs, xdbl, hs, Df, cat);
  // 6) out = cat @ W_out + b_out  (M=8192,N=1024,K=2048)
  gemm_tpl<true, true><<<dim3(DM / 128, MROWS / 128), 256, 0, stream>>>(
      flag, 1, cat, Wt_out, b_outf, d_out, MROWS, DM, DI);
  gemm_tpl<true, false><<<dim3(DM / 128, MROWS / 128), 256, 0, stream>>>(
      flag, 0, cat, Wt_out, b_outf, d_out, MROWS, DM, DI);
}

// Round 9
// 380.207 us; speedup vs baseline: 1.0894x; 1.0894x over previous
//
#include <hip/hip_runtime.h>
#include <hip/hip_bf16.h>
#include <math.h>

#define B_SZ 4
#define LSEQ 2048
#define DM 1024
#define DI 2048
#define DH 1024
#define DS 16
#define DTR 64
#define RTOT 96
#define MROWS (B_SZ * LSEQ) /* 8192 */

// scan chunking
#define NCH 32
#define CHUNK 64 /* LSEQ / NCH */

typedef short bf8_t __attribute__((ext_vector_type(8)));
typedef float f4_t __attribute__((ext_vector_type(4)));

__device__ __forceinline__ unsigned short f2bfbits(float v) {
  __hip_bfloat16 h = __float2bfloat16(v);
  return *(unsigned short*)&h;
}
__device__ __forceinline__ float bfu_lo(unsigned int v) {
  unsigned int x = v << 16;
  return *(float*)&x;
}
__device__ __forceinline__ float bfu_hi(unsigned int v) {
  unsigned int x = v & 0xffff0000u;
  return *(float*)&x;
}

// async global->LDS 16B per lane; LDS dest is wave-uniform base + lane*16
__device__ __forceinline__ void gl_lds16(const void* g, void* l) {
  __builtin_amdgcn_global_load_lds(
      (const __attribute__((address_space(1))) unsigned int*)g,
      (__attribute__((address_space(3))) unsigned int*)l,
      16, 0, 0);
}

__device__ __forceinline__ void ld8f(const float* p, unsigned short* d) {
  const float4 a = ((const float4*)p)[0];
  const float4 b = ((const float4*)p)[1];
  d[0] = f2bfbits(a.x); d[1] = f2bfbits(a.y); d[2] = f2bfbits(a.z); d[3] = f2bfbits(a.w);
  d[4] = f2bfbits(b.x); d[5] = f2bfbits(b.y); d[6] = f2bfbits(b.z); d[7] = f2bfbits(b.w);
}

// ---------------- dtype probe (1 = bf16 inputs, 0 = fp32 inputs) ----------------
__global__ void probe_kernel(const unsigned short* __restrict__ p, int* __restrict__ flag) {
  int lane = threadIdx.x;  // 64 lanes
  int sane = 0;
#pragma unroll
  for (int j = 0; j < 4; j++) {
    unsigned short lo = p[(lane * 4 + j) * 2];
    int e = (lo >> 7) & 0xFF;
    sane += (e <= 130) ? 1 : 0;
  }
  sane += __shfl_xor(sane, 1, 64);
  sane += __shfl_xor(sane, 2, 64);
  sane += __shfl_xor(sane, 4, 64);
  sane += __shfl_xor(sane, 8, 64);
  sane += __shfl_xor(sane, 16, 64);
  sane += __shfl_xor(sane, 32, 64);
  if (lane == 0) *flag = (sane >= 220) ? 1 : 0;
}

// ---------------- prep: canonicalize small weights to fp32 ----------------
// segments: conv_xw 4096 | conv_xb 1024 | conv_zw 4096 | conv_zb 1024 |
//           W_dt 65536 | inv_dt 1024 | Dvec 1024 | b_out 1024
#define PREP_TOT 78848
__global__ __launch_bounds__(256) void prep_kernel(
    const int* __restrict__ flag,
    const void* s0, const void* s1, const void* s2, const void* s3,
    const void* s4, const void* s5, const void* s6, const void* s7,
    float* __restrict__ out) {
  int i = blockIdx.x * 256 + threadIdx.x;
  if (i >= PREP_TOT) return;
  const void* src; int off;
  if      (i < 4096)   { src = s0; off = i; }
  else if (i < 5120)   { src = s1; off = i - 4096; }
  else if (i < 9216)   { src = s2; off = i - 5120; }
  else if (i < 10240)  { src = s3; off = i - 9216; }
  else if (i < 75776)  { src = s4; off = i - 10240; }
  else if (i < 76800)  { src = s5; off = i - 75776; }
  else if (i < 77824)  { src = s6; off = i - 76800; }
  else                 { src = s7; off = i - 77824; }
  float v = (*flag == 1) ? __bfloat162float(((const __hip_bfloat16*)src)[off])
                         : ((const float*)src)[off];
  out[i] = v;
}

// ---------------- transpose: Wt[n][k] bf16 <- W[k][n] (dtype by flag) ----------------
__global__ __launch_bounds__(256) void transpose_kernel(
    const int* __restrict__ flag, const void* __restrict__ W,
    unsigned short* __restrict__ Wt, int K, int N) {
  __shared__ unsigned short tile[32][33];
  int n0 = blockIdx.x * 32, k0 = blockIdx.y * 32;
  int c = threadIdx.x & 31, r8 = threadIdx.x >> 5;
  bool isbf = (*flag == 1);
#pragma unroll
  for (int p = 0; p < 4; p++) {
    int r = r8 + p * 8;
    unsigned short v;
    if (isbf) v = ((const unsigned short*)W)[(size_t)(k0 + r) * N + n0 + c];
    else      v = f2bfbits(((const float*)W)[(size_t)(k0 + r) * N + n0 + c]);
    tile[r][c] = v;
  }
  __syncthreads();
#pragma unroll
  for (int p = 0; p < 4; p++) {
    int r = r8 + p * 8;
    Wt[(size_t)(n0 + r) * K + k0 + c] = tile[c][r];
  }
}

// transpose W_xdbl [1024][96] -> Wxt [128][1024] bf16, rows 96..127 zero
__global__ __launch_bounds__(256) void transpose_pad_kernel(
    const int* __restrict__ flag, const void* __restrict__ W,
    unsigned short* __restrict__ Wt) {
  __shared__ unsigned short tile[32][33];
  int n0 = blockIdx.x * 32, k0 = blockIdx.y * 32;
  int c = threadIdx.x & 31, r8 = threadIdx.x >> 5;
  bool isbf = (*flag == 1);
#pragma unroll
  for (int p = 0; p < 4; p++) {
    int r = r8 + p * 8;
    unsigned short v = 0;
    if (n0 + c < RTOT) {
      if (isbf) v = ((const unsigned short*)W)[(size_t)(k0 + r) * RTOT + n0 + c];
      else      v = f2bfbits(((const float*)W)[(size_t)(k0 + r) * RTOT + n0 + c]);
    }
    tile[r][c] = v;
  }
  __syncthreads();
#pragma unroll
  for (int p = 0; p < 4; p++) {
    int r = r8 + p * 8;
    Wt[(size_t)(n0 + r) * DH + k0 + c] = tile[c][r];
  }
}

// ---------------- MFMA GEMM (B^T): C[M,N] = A[M,K] @ Bt[N,K]^T (+bias) ----------------
// 128x128 tile, BK=64 two-phase inner loop (half the barrier drains of BK=32;
// fragment regs reused across halves so VGPR stays at the BK=32 level).
// LDS 32KB/block. XOR swizzle on low 2 bits of the 16B-chunk index.
// XCD-aware block swizzle: each XCD (L&7 round-robin) owns contiguous M-bands.
template <bool A_BF, bool O_BF>
__global__ __launch_bounds__(256) void gemm_tpl(
    const int* __restrict__ flag, int want,
    const void* __restrict__ A, const unsigned short* __restrict__ Bt,
    const float* __restrict__ bias, void* __restrict__ C,
    int M, int N, int K) {
  if (*flag != want) return;
  __shared__ __align__(16) unsigned short As[128 * 64];
  __shared__ __align__(16) unsigned short Bs[128 * 64];
  const int tid = threadIdx.x;
  const int lane = tid & 63;
  const int wave = tid >> 6;
  const int quad = lane >> 4;
  const int l16 = lane & 15;
  const int wm = (wave & 1) * 64;
  const int wn = (wave >> 1) * 64;

  // XCD swizzle (MB % 8 == 0 for all call sites)
  const int NB = gridDim.x, MB = gridDim.y;
  int L = blockIdx.y * NB + blockIdx.x;
  int xcd = L & 7;
  int w = L >> 3;
  int m_band = xcd * (MB >> 3) + (w / NB);
  int n_blk = w % NB;
  const int m0 = m_band * 128;
  const int n0 = n_blk * 128;

  f4_t acc[4][4] = {};

  for (int k0 = 0; k0 < K; k0 += 64) {
    // stage A: 128 rows x 64 k = 1024 16B-chunks, 4/thread
#pragma unroll
    for (int j = 0; j < 4; j++) {
      int ch = tid + j * 256;
      int mi = ch >> 3;
      int s = ch & 7;
      int ki = (s & 4) | ((s & 3) ^ ((mi >> 1) & 3));
      if (A_BF) {
        gl_lds16((const unsigned short*)A + (size_t)(m0 + mi) * K + k0 + ki * 8,
                 &As[(j * 256 + wave * 64) * 8]);
      } else {
        unsigned short tmp[8];
        ld8f((const float*)A + (size_t)(m0 + mi) * K + k0 + ki * 8, tmp);
        *(uint4*)&As[ch * 8] = *(uint4*)tmp;
      }
    }
#pragma unroll
    for (int j = 0; j < 4; j++) {
      int ch = tid + j * 256;
      int ni = ch >> 3;
      int s = ch & 7;
      int ki = (s & 4) | ((s & 3) ^ ((ni >> 1) & 3));
      gl_lds16(Bt + (size_t)(n0 + ni) * K + k0 + ki * 8,
               &Bs[(j * 256 + wave * 64) * 8]);
    }
    __syncthreads();

#pragma unroll
    for (int h = 0; h < 2; h++) {
      bf8_t af[4], bfr[4];
#pragma unroll
      for (int ti = 0; ti < 4; ti++) {
        int r = wm + ti * 16 + l16;
        af[ti] = *(const bf8_t*)&As[(r * 8 + h * 4 + (quad ^ ((r >> 1) & 3))) * 8];
      }
#pragma unroll
      for (int tj = 0; tj < 4; tj++) {
        int r = wn + tj * 16 + l16;
        bfr[tj] = *(const bf8_t*)&Bs[(r * 8 + h * 4 + (quad ^ ((r >> 1) & 3))) * 8];
      }
#pragma unroll
      for (int ti = 0; ti < 4; ti++)
#pragma unroll
        for (int tj = 0; tj < 4; tj++)
          acc[ti][tj] = __builtin_amdgcn_mfma_f32_16x16x32_bf16(
              af[ti], bfr[tj], acc[ti][tj], 0, 0, 0);
    }
    __syncthreads();
  }

  // epilogue: C/D layout col=lane&15, row=quad*4+reg (verified m89/m91)
#pragma unroll
  for (int ti = 0; ti < 4; ti++) {
#pragma unroll
    for (int tj = 0; tj < 4; tj++) {
      int col = n0 + wn + tj * 16 + l16;
      float bv = bias ? bias[col] : 0.f;
#pragma unroll
      for (int r = 0; r < 4; r++) {
        int row = m0 + wm + ti * 16 + quad * 4 + r;
        float v = acc[ti][tj][r] + bv;
        if (O_BF) ((__hip_bfloat16*)C)[(size_t)row * N + col] = __float2bfloat16(v);
        else      ((float*)C)[(size_t)row * N + col] = v;
      }
    }
  }
}

// ---------------- xdbl MFMA: xdbl[M,96] = xs_bf[M,1024] @ Wxt[96,1024]^T ----------------
__global__ __launch_bounds__(256) void xdbl_mfma_kernel(
    const unsigned short* __restrict__ A, const unsigned short* __restrict__ Bt,
    float* __restrict__ xdbl) {
  __shared__ __align__(16) unsigned short As[64 * 32];
  __shared__ __align__(16) unsigned short Bs[128 * 32];
  const int tid = threadIdx.x;
  const int lane = tid & 63;
  const int wave = tid >> 6;
  const int quad = lane >> 4;
  const int l16 = lane & 15;
  const int m0 = blockIdx.x * 64;

  f4_t acc[6] = {};

  for (int k0 = 0; k0 < DH; k0 += 32) {
    {
      int ch = tid;  // 256 chunks for A
      int mi = ch >> 2;
      int ki = (ch & 3) ^ ((mi >> 1) & 3);
      gl_lds16(A + (size_t)(m0 + mi) * DH + k0 + ki * 8, &As[(wave * 64) * 8]);
    }
#pragma unroll
    for (int j = 0; j < 2; j++) {
      int ch = tid + j * 256;
      int ni = ch >> 2;
      int ki = (ch & 3) ^ ((ni >> 1) & 3);
      gl_lds16(Bt + (size_t)ni * DH + k0 + ki * 8, &Bs[(j * 256 + wave * 64) * 8]);
    }
    __syncthreads();

    bf8_t af, bfr[6];
    {
      int r = wave * 16 + l16;
      af = *(const bf8_t*)&As[(r * 4 + (quad ^ ((r >> 1) & 3))) * 8];
    }
#pragma unroll
    for (int tj = 0; tj < 6; tj++) {
      int r = tj * 16 + l16;
      bfr[tj] = *(const bf8_t*)&Bs[(r * 4 + (quad ^ ((r >> 1) & 3))) * 8];
    }
#pragma unroll
    for (int tj = 0; tj < 6; tj++)
      acc[tj] = __builtin_amdgcn_mfma_f32_16x16x32_bf16(af, bfr[tj], acc[tj], 0, 0, 0);
    __syncthreads();
  }

#pragma unroll
  for (int tj = 0; tj < 6; tj++) {
    int col = tj * 16 + l16;
#pragma unroll
    for (int r = 0; r < 4; r++) {
      int row = m0 + wave * 16 + quad * 4 + r;
      xdbl[(size_t)row * RTOT + col] = acc[tj][r];
    }
  }
}

// ---------------- depthwise conv (k=4, SAME: pad_low=1) + SiLU, 8 ch/thread ----------------
__global__ __launch_bounds__(256) void conv_silu_kernel(
    const unsigned short* __restrict__ xz,
    const float* __restrict__ wx, const float* __restrict__ bx,
    const float* __restrict__ wz, const float* __restrict__ bz,
    unsigned short* __restrict__ xs_bf, unsigned short* __restrict__ cat) {
  int gid = blockIdx.x * 256 + threadIdx.x;  // M*128 threads
  int cg = gid & 127;
  int c0 = cg * 8;
  int m = gid >> 7;
  int t = m & (LSEQ - 1);
  float ax[8], az[8];
#pragma unroll
  for (int i = 0; i < 8; i++) { ax[i] = bx[c0 + i]; az[i] = bz[c0 + i]; }
#pragma unroll
  for (int j = 0; j < 4; j++) {
    int tt = t - 1 + j;
    if (tt < 0 || tt >= LSEQ) continue;
    size_t row = (size_t)(m - t + tt);
    uint4 vx = *(const uint4*)&xz[row * DI + c0];
    uint4 vz = *(const uint4*)&xz[row * DI + DH + c0];
    const unsigned int* px = (const unsigned int*)&vx;
    const unsigned int* pz = (const unsigned int*)&vz;
#pragma unroll
    for (int q = 0; q < 4; q++) {
      float x0 = bfu_lo(px[q]), x1 = bfu_hi(px[q]);
      float z0 = bfu_lo(pz[q]), z1 = bfu_hi(pz[q]);
      ax[q * 2]     = fmaf(wx[j * DH + c0 + q * 2], x0, ax[q * 2]);
      ax[q * 2 + 1] = fmaf(wx[j * DH + c0 + q * 2 + 1], x1, ax[q * 2 + 1]);
      az[q * 2]     = fmaf(wz[j * DH + c0 + q * 2], z0, az[q * 2]);
      az[q * 2 + 1] = fmaf(wz[j * DH + c0 + q * 2 + 1], z1, az[q * 2 + 1]);
    }
  }
  unsigned short sx[8], sz[8];
#pragma unroll
  for (int i = 0; i < 8; i++) {
    float vx = ax[i] / (1.f + __expf(-ax[i]));
    float vz = az[i] / (1.f + __expf(-az[i]));
    sx[i] = f2bfbits(vx);
    sz[i] = f2bfbits(vz);
  }
  *(uint4*)&xs_bf[(size_t)m * DH + c0] = *(uint4*)sx;
  *(uint4*)&cat[(size_t)m * DI + DH + c0] = *(uint4*)sz;
}

// ---------------- delta+u pack: du[m][d] = (bf16(softplus), bf16(u)) ----------------
__global__ __launch_bounds__(256) void delta_kernel(
    const float* __restrict__ xdbl, const float* __restrict__ Wdt,
    const float* __restrict__ inv_dt, const unsigned short* __restrict__ xs,
    unsigned int* __restrict__ du) {
  const int d = blockIdx.x * 256 + threadIdx.x;  // blockIdx.x in [0,4)
  const int m0 = blockIdx.y * 8;
  __shared__ float xr[8][DTR];
#pragma unroll
  for (int i = 0; i < 2; i++) {
    int e = threadIdx.x + i * 256;  // 512 = 8*64
    xr[e >> 6][e & 63] = xdbl[(size_t)(m0 + (e >> 6)) * RTOT + (e & 63)];
  }
  __syncthreads();
  float acc[8];
#pragma unroll
  for (int i = 0; i < 8; i++) acc[i] = 0.f;
  for (int rr = 0; rr < DTR; rr++) {
    float w = Wdt[(size_t)rr * DH + d];
#pragma unroll
    for (int i = 0; i < 8; i++) acc[i] = fmaf(xr[i][rr], w, acc[i]);
  }
  const float bias2 = 2.f * inv_dt[d];
#pragma unroll
  for (int i = 0; i < 8; i++) {
    float v = acc[i] + bias2;
    float sp = (v > 0.f) ? (v + log1pf(__expf(-v))) : log1pf(__expf(v));
    unsigned int lo = f2bfbits(sp);
    unsigned int hi = xs[(size_t)(m0 + i) * DH + d];
    du[(size_t)(m0 + i) * DH + d] = lo | (hi << 16);
  }
}

// ---------------- chunked selective scan (packed du) ----------------
__global__ __launch_bounds__(256) void scan_pass1(
    const unsigned int* __restrict__ du, const float* __restrict__ xdbl,
    float* __restrict__ Echunks, float* __restrict__ hp) {
  const int tid = threadIdx.x;
  const int d = blockIdx.x * 256 + tid;
  const int c = blockIdx.y, b = blockIdx.z;
  const int row0 = b * LSEQ + c * CHUNK;
  __shared__ float sBC[CHUNK][32];  // [t][0..15]=B, [16..31]=C
#pragma unroll
  for (int i = 0; i < 2; i++) {
    int task = tid + i * 256;
    int r = task >> 3, seg = task & 7;
    *(float4*)&sBC[r][seg * 4] =
        *(const float4*)&xdbl[(size_t)(row0 + r) * RTOT + DTR + seg * 4];
  }
  __syncthreads();
  float h[16];
#pragma unroll
  for (int n = 0; n < 16; n++) h[n] = 0.f;
  float E = 1.f;
  for (int t = 0; t < CHUNK; t++) {
    unsigned int v = du[(size_t)(row0 + t) * DH + d];
    float dt = bfu_lo(v), ut = bfu_hi(v);
    float e = __expf(-dt);
    E *= e;
    float dv = dt * ut;
    float p = 1.f;
#pragma unroll
    for (int n = 0; n < 16; n++) {
      p *= e;
      h[n] = fmaf(p, h[n], dv * sBC[t][n]);
    }
  }
  Echunks[((size_t)c * B_SZ + b) * DH + d] = E;
#pragma unroll
  for (int n = 0; n < 16; n++)
    hp[(((size_t)c * B_SZ + b) * 16 + n) * DH + d] = h[n];
}

__global__ __launch_bounds__(256) void scan_pass2(
    const float* __restrict__ Echunks, const float* __restrict__ hp,
    float* __restrict__ hs) {
  int t = blockIdx.x * 256 + threadIdx.x;
  int d = t & 1023;
  int n = (t >> 10) & 15;
  int b = t >> 14;
  float h = 0.f;
  const int k0 = n + 1;
  for (int c = 0; c < NCH; c++) {
    float E = Echunks[((size_t)c * B_SZ + b) * DH + d];
    float a = 1.f, base = E;
    int k = k0;
#pragma unroll
    for (int i = 0; i < 5; i++) {
      if (k & 1) a *= base;
      base *= base;
      k >>= 1;
    }
    size_t idx = (((size_t)c * B_SZ + b) * 16 + n) * DH + d;
    hs[idx] = h;
    h = fmaf(a, h, hp[idx]);
  }
}

__global__ __launch_bounds__(256) void scan_pass3(
    const unsigned int* __restrict__ du, const float* __restrict__ xdbl,
    const float* __restrict__ hs, const float* __restrict__ Dvec,
    __hip_bfloat16* __restrict__ cat) {
  const int tid = threadIdx.x;
  const int d = blockIdx.x * 256 + tid;
  const int c = blockIdx.y, b = blockIdx.z;
  const int row0 = b * LSEQ + c * CHUNK;
  __shared__ float sBC[CHUNK][32];
#pragma unroll
  for (int i = 0; i < 2; i++) {
    int task = tid + i * 256;
    int r = task >> 3, seg = task & 7;
    *(float4*)&sBC[r][seg * 4] =
        *(const float4*)&xdbl[(size_t)(row0 + r) * RTOT + DTR + seg * 4];
  }
  __syncthreads();
  float h[16];
#pragma unroll
  for (int n = 0; n < 16; n++)
    h[n] = hs[(((size_t)c * B_SZ + b) * 16 + n) * DH + d];
  const float Dd = Dvec[d];
  for (int t = 0; t < CHUNK; t++) {
    unsigned int v = du[(size_t)(row0 + t) * DH + d];
    float dt = bfu_lo(v), ut = bfu_hi(v);
    float e = __expf(-dt);
    float dv = dt * ut;
    float p = 1.f, y = 0.f;
#pragma unroll
    for (int n = 0; n < 16; n++) {
      p *= e;
      h[n] = fmaf(p, h[n], dv * sBC[t][n]);
      y = fmaf(h[n], sBC[t][16 + n], y);
    }
    y = fmaf(ut, Dd, y);
    cat[(size_t)(row0 + t) * DI + d] = __float2bfloat16(y);
  }
}

extern "C" void kernel_launch(void* const* d_in, const int* in_sizes, int n_in,
                              void* d_out, int out_size, void* d_ws, size_t ws_size,
                              hipStream_t stream) {
  char* ws = (char*)d_ws;
  // layout (MB offsets):
  // [0,32): xz bf16 [8192][2048]; later du uint32 [8192][1024] (xz dead after conv)
  // [32,48): xs bf16 [8192][1024]
  // [64,96): cat bf16 (y cols 0..1023, z cols 1024..2047)
  // [96,99): xdbl fp32 [8192][96]
  // [99,99.5): Echunks | [100,108): hp | [108,116): hs
  // [116,120): Wt_in bf16 | [120,124): Wt_out bf16 | [124,124.25): Wxt bf16 [128][1024]
  // [125,+316KB): canonical fp32 weights | [126]: flag
  __hip_bfloat16* xz  = (__hip_bfloat16*)(ws);
  unsigned int* du    = (unsigned int*)(ws);
  __hip_bfloat16* xs  = (__hip_bfloat16*)(ws + ((size_t)32 << 20));
  __hip_bfloat16* cat = (__hip_bfloat16*)(ws + ((size_t)64 << 20));
  float* xdbl         = (float*)(ws + ((size_t)96 << 20));
  float* Echunks      = (float*)(ws + ((size_t)99 << 20));
  float* hp           = (float*)(ws + ((size_t)100 << 20));
  float* hs           = (float*)(ws + ((size_t)108 << 20));
  unsigned short* Wt_in  = (unsigned short*)(ws + ((size_t)116 << 20));
  unsigned short* Wt_out = (unsigned short*)(ws + ((size_t)120 << 20));
  unsigned short* Wxt    = (unsigned short*)(ws + ((size_t)124 << 20));
  float* cw           = (float*)(ws + ((size_t)125 << 20));
  int* flag           = (int*)(ws + ((size_t)126 << 20));

  const float* conv_xwf = cw + 0;
  const float* conv_xbf = cw + 4096;
  const float* conv_zwf = cw + 5120;
  const float* conv_zbf = cw + 9216;
  const float* Wdtf     = cw + 10240;
  const float* inv_dtf  = cw + 75776;
  const float* Df       = cw + 76800;
  const float* b_outf   = cw + 77824;

  probe_kernel<<<1, 64, 0, stream>>>((const unsigned short*)d_in[0], flag);
  prep_kernel<<<(PREP_TOT + 255) / 256, 256, 0, stream>>>(
      flag, d_in[2], d_in[3], d_in[4], d_in[5], d_in[7], d_in[8], d_in[9],
      d_in[11], cw);
  transpose_kernel<<<dim3(DI / 32, DM / 32), 256, 0, stream>>>(
      flag, d_in[1], Wt_in, DM, DI);
  transpose_kernel<<<dim3(DM / 32, DI / 32), 256, 0, stream>>>(
      flag, d_in[10], Wt_out, DI, DM);
  transpose_pad_kernel<<<dim3(4, DH / 32), 256, 0, stream>>>(flag, d_in[6], Wxt);

  // 1) xz = x @ W_in  (M=8192,N=2048,K=1024), out bf16. Dead-launch dtype variants.
  gemm_tpl<true, true><<<dim3(DI / 128, MROWS / 128), 256, 0, stream>>>(
      flag, 1, d_in[0], Wt_in, (const float*)nullptr, xz, MROWS, DI, DM);
  gemm_tpl<false, true><<<dim3(DI / 128, MROWS / 128), 256, 0, stream>>>(
      flag, 0, d_in[0], Wt_in, (const float*)nullptr, xz, MROWS, DI, DM);
  // 2) conv + silu -> xs bf16, cat z-half
  conv_silu_kernel<<<(MROWS * 128) / 256, 256, 0, stream>>>(
      (const unsigned short*)xz, conv_xwf, conv_xbf, conv_zwf, conv_zbf,
      (unsigned short*)xs, (unsigned short*)cat);
  // 3) x_dbl = xs @ W_xdbl via MFMA
  xdbl_mfma_kernel<<<MROWS / 64, 256, 0, stream>>>(
      (const unsigned short*)xs, Wxt, xdbl);
  // 4) delta+u pack (overwrites dead xz region)
  delta_kernel<<<dim3(4, MROWS / 8), 256, 0, stream>>>(
      xdbl, Wdtf, inv_dtf, (const unsigned short*)xs, du);
  // 5) chunked scan
  scan_pass1<<<dim3(4, NCH, B_SZ), 256, 0, stream>>>(du, xdbl, Echunks, hp);
  scan_pass2<<<256, 256, 0, stream>>>(Echunks, hp, hs);
  scan_pass3<<<dim3(4, NCH, B_SZ), 256, 0, stream>>>(du, xdbl, hs, Df, cat);
  // 6) out = cat @ W_out + b_out  (M=8192,N=1024,K=2048)
  gemm_tpl<true, true><<<dim3(DM / 128, MROWS / 128), 256, 0, stream>>>(
      flag, 1, cat, Wt_out, b_outf, d_out, MROWS, DM, DI);
  gemm_tpl<true, false><<<dim3(DM / 128, MROWS / 128), 256, 0, stream>>>(
      flag, 0, cat, Wt_out, b_outf, d_out, MROWS, DM, DI);
}